// Round 4
// baseline (368.510 us; speedup 1.0000x reference)
//
#include <hip/hip_runtime.h>

#define N_NODES 100000
#define DIM 128

typedef __attribute__((ext_vector_type(8))) short bf16x8;
typedef __attribute__((ext_vector_type(4))) float f32x4;
typedef __attribute__((ext_vector_type(8))) unsigned short ushort8;

__device__ __forceinline__ unsigned short f2bf(float f) {
    union { float f; unsigned u; } v; v.f = f;
    unsigned u = v.u + 0x7FFFu + ((v.u >> 16) & 1u);
    return (unsigned short)(u >> 16);
}

__device__ __forceinline__ void gload_lds16(const void* g, void* l) {
    __builtin_amdgcn_global_load_lds((const __attribute__((address_space(1))) void*)g,
                                     (__attribute__((address_space(3))) void*)l, 16, 0, 0);
}

// ---------------- x -> bf16 ----------------
__global__ void cvt_x_kernel(const float* __restrict__ x, unsigned short* __restrict__ xb,
                             int n8) {
    int i = blockIdx.x * 256 + threadIdx.x;
    if (i < n8) {
        const float4* p = reinterpret_cast<const float4*>(x) + (size_t)i * 2;
        float4 a = p[0], b = p[1];
        ushort8 o;
        o[0] = f2bf(a.x); o[1] = f2bf(a.y); o[2] = f2bf(a.z); o[3] = f2bf(a.w);
        o[4] = f2bf(b.x); o[5] = f2bf(b.y); o[6] = f2bf(b.z); o[7] = f2bf(b.w);
        *reinterpret_cast<ushort8*>(xb + (size_t)i * 8) = o;
    }
}

// ---------------- all weight matrices -> bf16 slice layout ----------------
// bts: 7 slices of [128][128]: 0=A1; 1,2=A2; 3,4,5=A3; 6=Cw.
// slice[a][c][k'] = A[a*128+k'][c]   (Cw: [c][k] as-is)
__global__ void cvt_B_all(const float* __restrict__ A1, const float* __restrict__ A2,
                          const float* __restrict__ A3, const float* __restrict__ Cw,
                          unsigned short* __restrict__ bts) {
    int kg = blockIdx.x;   // 0..895
    int c = threadIdx.x;   // 0..127
    float v;
    int slice, kp;
    if (kg < 128)      { slice = 0; kp = kg; v = A1[(size_t)kg * 128 + c]; }
    else if (kg < 384) { int k = kg - 128; slice = 1 + (k >> 7); kp = k & 127; v = A2[(size_t)k * 128 + c]; }
    else if (kg < 768) { int k = kg - 384; slice = 3 + (k >> 7); kp = k & 127; v = A3[(size_t)k * 128 + c]; }
    else               { int k = kg - 768; slice = 6; kp = k; v = Cw[(size_t)c * 128 + k]; }
    bts[(size_t)slice * 16384 + c * 128 + kp] = f2bf(v);
}

// ---------------- fused counts (all 3 edge types) ----------------
__global__ void count_all_kernel(const int* __restrict__ e1d, const int* __restrict__ e2d,
                                 const int* __restrict__ e3d, int ng1, int ng12, int ngall,
                                 int* __restrict__ counts) {
    int g = blockIdx.x * 256 + threadIdx.x;
    if (g < ng1) atomicAdd(&counts[e1d[g]], 1);
    else if (g < ng12) atomicAdd(&counts[N_NODES + e2d[(size_t)(g - ng1) * 2]], 1);
    else if (g < ngall) atomicAdd(&counts[2 * N_NODES + e3d[(size_t)(g - ng12) * 3]], 1);
}

// ---------------- hierarchical scan ----------------
__global__ __launch_bounds__(256) void scan_p1(const int* __restrict__ counts,
                                               int* __restrict__ partials) {
    __shared__ int red[256];
    int type = blockIdx.y, blk = blockIdx.x, tid = threadIdx.x;
    int base = blk * 4096 + tid * 16;
    int s = 0;
#pragma unroll
    for (int j = 0; j < 16; ++j) {
        int i = base + j;
        s += (i < N_NODES) ? counts[(size_t)type * N_NODES + i] : 0;
    }
    red[tid] = s;
    __syncthreads();
    for (int off = 128; off > 0; off >>= 1) {
        if (tid < off) red[tid] += red[tid + off];
        __syncthreads();
    }
    if (tid == 0) partials[type * 32 + blk] = red[0];
}

__global__ void scan_p2(int* __restrict__ partials) {
    int t = threadIdx.x;
    if (t < 3) {
        int run = 0;
        for (int b = 0; b < 25; ++b) {
            int v = partials[t * 32 + b];
            partials[t * 32 + b] = run;
            run += v;
        }
    }
}

__global__ __launch_bounds__(256) void scan_p3(const int* __restrict__ counts,
                                               const int* __restrict__ partials,
                                               int* __restrict__ cursor) {
    __shared__ int tsum[256];
    int type = blockIdx.y, blk = blockIdx.x, tid = threadIdx.x;
    int base = blk * 4096 + tid * 16;
    int v[16];
    int s = 0;
#pragma unroll
    for (int j = 0; j < 16; ++j) {
        int i = base + j;
        v[j] = (i < N_NODES) ? counts[(size_t)type * N_NODES + i] : 0;
        s += v[j];
    }
    tsum[tid] = s;
    __syncthreads();
    for (int off = 1; off < 256; off <<= 1) {
        int t2 = (tid >= off) ? tsum[tid - off] : 0;
        __syncthreads();
        tsum[tid] += t2;
        __syncthreads();
    }
    int run = tsum[tid] - s + partials[type * 32 + blk];
#pragma unroll
    for (int j = 0; j < 16; ++j) {
        int i = base + j;
        if (i < N_NODES) cursor[(size_t)type * N_NODES + i] = run;
        run += v[j];
    }
}

// ---------------- fused counting-sort scatter ----------------
__global__ void scatter_all_kernel(const int* __restrict__ e1d, const int* __restrict__ e2d,
                                   const int* __restrict__ e3d, int ng1, int ng12, int ngall,
                                   int* __restrict__ cursor, int* __restrict__ s1,
                                   int* __restrict__ s2, int* __restrict__ s3) {
    int g = blockIdx.x * 256 + threadIdx.x;
    if (g < ng1) {
        int d = e1d[g];
        s1[atomicAdd(&cursor[d], 1)] = g;
    } else if (g < ng12) {
        int k = g - ng1;
        int d = e2d[(size_t)k * 2];
        s2[atomicAdd(&cursor[N_NODES + d], 1)] = k;
    } else if (g < ngall) {
        int k = g - ng12;
        int d = e3d[(size_t)k * 3];
        s3[atomicAdd(&cursor[2 * N_NODES + d], 1)] = k;
    }
}

// ---------------- MFMA GEMM (gather + scatter fused), counted-vmcnt pipeline ---
// LDS: [0,32768) = 4 x 8192 S buffers; then nodebuf[3][128], destbuf[128], invbuf[128].
// Epilogue reuses [0,16896) as float Ep[32][132].
template <int ARITY, int MODE>
__global__ __launch_bounds__(256, 3) void hgnn_mfma_kernel(
    const unsigned short* __restrict__ xb,   // [N_NODES][128] bf16
    const int* __restrict__ idx0,
    const int* __restrict__ idx1,
    const int* __restrict__ sorted,
    const unsigned short* __restrict__ BTs,  // [ARITY][128][128] bf16 slices
    const int* __restrict__ counts,
    const float* __restrict__ bias,
    float* __restrict__ out,
    int ngroups)
{
    constexpr int NSTEPS = 4 * ARITY;
    constexpr int NOFF = 32768, DOFF = NOFF + 1536, IOFF = DOFF + 512;

    __shared__ __align__(16) char smem[IOFF + 512];
    int* nodebuf = (int*)(smem + NOFF);
    int* destbuf = (int*)(smem + DOFF);
    float* invbuf = (float*)(smem + IOFF);

    const int tid = threadIdx.x;
    const int w = tid >> 6, l = tid & 63;
    const int g0 = blockIdx.x * 128;
    const int lrow = l & 15, lk = l >> 4;
    const int wr = (w & 1) * 64, wc = (w >> 1) * 64;

    if (MODE == 0) {
        if (tid < 128) {
            int g = g0 + tid;
            int sg = (g < ngroups) ? sorted[g] : 0;
            int d = (g < ngroups) ? idx1[(size_t)sg * ARITY] : -1;
            destbuf[tid] = d;
            invbuf[tid] = (g < ngroups) ? (1.0f / (float)counts[d]) : 0.f;
#pragma unroll
            for (int a = 0; a < ARITY; ++a)
                nodebuf[a * 128 + tid] = (g < ngroups) ? idx0[(size_t)sg * ARITY + a] : 0;
        }
        __syncthreads();
    }

    // per-lane staging constants (inverse of the read-side XOR swizzle)
    const int q = (((l & 7) ^ (l >> 3)) << 4);
    const int inner = q & 63;
    const int rpq = ((l >> 3) << 1) + (q >> 6);

    // A-fragment read offsets (XOR-swizzled), within one 8 KB S buffer
    int aoff[4];
#pragma unroll
    for (int mi = 0; mi < 4; ++mi) {
        int r = wr + mi * 16 + lrow;
        int P = r >> 1;
        aoff[mi] = P * 128 + ((((r & 1) << 6) | (lk << 4)) ^ ((P & 7) << 4));
    }

    f32x4 acc[4][4];
#pragma unroll
    for (int mi = 0; mi < 4; ++mi)
#pragma unroll
        for (int ni = 0; ni < 4; ++ni) acc[mi][ni] = (f32x4){0.f, 0.f, 0.f, 0.f};

    auto STAGE = [&](int kc, int buf) {
        const int a = kc >> 2;
        const int f0b = (kc & 3) * 64;
#pragma unroll
        for (int i = 0; i < 2; ++i) {
            int u = w * 2 + i;
            int r = u * 16 + rpq;
            int node;
            if (MODE == 1) {
                int gg = g0 + r;
                node = (gg < ngroups) ? gg : 0;
            } else {
                node = nodebuf[a * 128 + r];
            }
            gload_lds16((const char*)xb + (size_t)node * 256 + f0b + inner,
                        smem + buf * 8192 + u * 1024);
        }
    };

    auto LOADB = [&](int a, int kc, bf16x8 (&dst)[4]) {
#pragma unroll
        for (int ni = 0; ni < 4; ++ni)
            dst[ni] = *reinterpret_cast<const bf16x8*>(
                BTs + (size_t)a * 16384 + (wc + ni * 16 + lrow) * 128 + kc * 32 + lk * 8);
    };

    bf16x8 bgA[4], bgB[4];
    LOADB(0, 0, bgA);
    STAGE(0, 0);
    STAGE(1, 1);
    STAGE(2, 2);
    asm volatile("s_waitcnt vmcnt(4)" ::: "memory");
    __builtin_amdgcn_s_barrier();
    asm volatile("" ::: "memory");

    auto BODY = [&](int t, bf16x8 (&bgc)[4], bf16x8 (&bgn)[4]) {
        const int buf = t & 3;
        if (t + 1 < NSTEPS) LOADB((t + 1) >> 2, (t + 1) & 3, bgn);
        if (t + 3 < NSTEPS) STAGE(t + 3, (t + 3) & 3);
        bf16x8 af[4];
#pragma unroll
        for (int mi = 0; mi < 4; ++mi)
            af[mi] = *reinterpret_cast<const bf16x8*>(smem + buf * 8192 + aoff[mi]);
        __builtin_amdgcn_s_setprio(1);
#pragma unroll
        for (int mi = 0; mi < 4; ++mi)
#pragma unroll
            for (int ni = 0; ni < 4; ++ni)
                acc[mi][ni] = __builtin_amdgcn_mfma_f32_16x16x32_bf16(
                    af[mi], bgc[ni], acc[mi][ni], 0, 0, 0);
        __builtin_amdgcn_s_setprio(0);
        // counted vmcnt: keep future stages in flight across the barrier.
        if (t == NSTEPS - 1)      asm volatile("s_waitcnt vmcnt(0)" ::: "memory");
        else if (t == NSTEPS - 2) asm volatile("s_waitcnt vmcnt(4)" ::: "memory");
        else if (t == NSTEPS - 3) asm volatile("s_waitcnt vmcnt(6)" ::: "memory");
        else                      asm volatile("s_waitcnt vmcnt(8)" ::: "memory");
        __builtin_amdgcn_s_barrier();
        asm volatile("" ::: "memory");
    };

#pragma unroll
    for (int t = 0; t < NSTEPS; t += 2) {
        BODY(t, bgA, bgB);
        BODY(t + 1, bgB, bgA);
    }

    if (MODE == 1) {
        float bv[4];
#pragma unroll
        for (int ni = 0; ni < 4; ++ni) bv[ni] = bias[wc + ni * 16 + lrow];
#pragma unroll
        for (int mi = 0; mi < 4; ++mi) {
#pragma unroll
            for (int reg = 0; reg < 4; ++reg) {
                int g = g0 + wr + mi * 16 + lk * 4 + reg;
                if (g < ngroups) {
#pragma unroll
                    for (int ni = 0; ni < 4; ++ni)
                        out[(size_t)g * DIM + wc + ni * 16 + lrow] = acc[mi][ni][reg] + bv[ni];
                }
            }
        }
    } else {
        float* Ep = (float*)smem;  // [32][132]
#pragma unroll
        for (int c0 = 0; c0 < 128; c0 += 32) {
            if ((w & 1) == (c0 >> 6)) {
                const int m0 = (c0 & 63) >> 4;
#pragma unroll
                for (int mm = 0; mm < 2; ++mm) {
                    const int mi = m0 + mm;
                    const int lr = mm * 16 + lk * 4;
#pragma unroll
                    for (int ni = 0; ni < 4; ++ni) {
                        const int col = wc + ni * 16 + lrow;
#pragma unroll
                        for (int reg = 0; reg < 4; ++reg)
                            Ep[(lr + reg) * 132 + col] = acc[mi][ni][reg];
                    }
                }
            }
            __syncthreads();
            int cur = -1;
            float r0 = 0.f, r1 = 0.f;
#pragma unroll
            for (int r = 0; r < 8; ++r) {
                int row = w * 8 + r;
                int g = g0 + c0 + row;
                if (g < ngroups) {
                    int d = destbuf[c0 + row];
                    float inv = invbuf[c0 + row];
                    if (d != cur) {
                        if (cur >= 0) {
                            float* op = out + (size_t)cur * DIM;
                            __hip_atomic_fetch_add(&op[l], r0, __ATOMIC_RELAXED,
                                                   __HIP_MEMORY_SCOPE_AGENT);
                            __hip_atomic_fetch_add(&op[l + 64], r1, __ATOMIC_RELAXED,
                                                   __HIP_MEMORY_SCOPE_AGENT);
                        }
                        cur = d;
                        r0 = 0.f;
                        r1 = 0.f;
                    }
                    r0 += Ep[row * 132 + l] * inv;
                    r1 += Ep[row * 132 + 64 + l] * inv;
                }
            }
            if (cur >= 0) {
                float* op = out + (size_t)cur * DIM;
                __hip_atomic_fetch_add(&op[l], r0, __ATOMIC_RELAXED,
                                       __HIP_MEMORY_SCOPE_AGENT);
                __hip_atomic_fetch_add(&op[l + 64], r1, __ATOMIC_RELAXED,
                                       __HIP_MEMORY_SCOPE_AGENT);
            }
            __syncthreads();
        }
    }
}

extern "C" void kernel_launch(void* const* d_in, const int* in_sizes, int n_in,
                              void* d_out, int out_size, void* d_ws, size_t ws_size,
                              hipStream_t stream) {
    const float* x  = (const float*)d_in[0];
    const int*   e1 = (const int*)d_in[1];
    const int*   e2 = (const int*)d_in[2];
    const int*   e3 = (const int*)d_in[3];
    const float* A1 = (const float*)d_in[4];
    const float* A2 = (const float*)d_in[5];
    const float* A3 = (const float*)d_in[6];
    const float* Cw = (const float*)d_in[7];
    const float* Cb = (const float*)d_in[8];
    float* out = (float*)d_out;

    const int ne1 = in_sizes[1] / 2, ne2 = in_sizes[2] / 2, ne3 = in_sizes[3] / 2;
    const int ng1 = ne1, ng2 = ne2 / 2, ng3 = ne3 / 3;
    const int N = N_NODES;

    int* counts  = (int*)d_ws;          // 3*N
    int* cursor  = counts + 3 * N;      // 3*N
    int* sorted1 = cursor + 3 * N;
    int* sorted2 = sorted1 + ng1;
    int* sorted3 = sorted2 + ng2;
    int* partials = sorted3 + ng3;      // 96 used, pad 128
    unsigned short* bts = (unsigned short*)(partials + 128);  // 7 * 16384
    unsigned short* xb  = bts + 7 * 16384;

    hipMemsetAsync(counts, 0, (size_t)3 * N * sizeof(int), stream);
    cvt_x_kernel<<<(N * DIM / 8 + 255) / 256, 256, 0, stream>>>(x, xb, N * DIM / 8);
    cvt_B_all<<<896, 128, 0, stream>>>(A1, A2, A3, Cw, bts);

    const int ngall = ng1 + ng2 + ng3;
    count_all_kernel<<<(ngall + 255) / 256, 256, 0, stream>>>(
        e1 + ne1, e2 + ne2, e3 + ne3, ng1, ng1 + ng2, ngall, counts);
    scan_p1<<<dim3(25, 3), 256, 0, stream>>>(counts, partials);
    scan_p2<<<1, 64, 0, stream>>>(partials);
    scan_p3<<<dim3(25, 3), 256, 0, stream>>>(counts, partials, cursor);
    scatter_all_kernel<<<(ngall + 255) / 256, 256, 0, stream>>>(
        e1 + ne1, e2 + ne2, e3 + ne3, ng1, ng1 + ng2, ngall, cursor,
        sorted1, sorted2, sorted3);

    // dense first (initializes every out row), then edge kernels atomically add
    hgnn_mfma_kernel<1, 1><<<(N + 127) / 128, 256, 0, stream>>>(
        xb, nullptr, nullptr, nullptr, bts + 6 * 16384, nullptr, Cb, out, N);
    hgnn_mfma_kernel<1, 0><<<(ng1 + 127) / 128, 256, 0, stream>>>(
        xb, e1, e1 + ne1, sorted1, bts, counts, nullptr, out, ng1);
    hgnn_mfma_kernel<2, 0><<<(ng2 + 127) / 128, 256, 0, stream>>>(
        xb, e2, e2 + ne2, sorted2, bts + 16384, counts + N, nullptr, out, ng2);
    hgnn_mfma_kernel<3, 0><<<(ng3 + 127) / 128, 256, 0, stream>>>(
        xb, e3, e3 + ne3, sorted3, bts + 3 * 16384, counts + 2 * N, nullptr, out, ng3);
}

// Round 5
// 310.523 us; speedup vs baseline: 1.1867x; 1.1867x over previous
//
#include <hip/hip_runtime.h>

#define N_NODES 100000
#define DIM 128

typedef __attribute__((ext_vector_type(8))) short bf16x8;
typedef __attribute__((ext_vector_type(4))) float f32x4;
typedef __attribute__((ext_vector_type(8))) unsigned short ushort8;

__device__ __forceinline__ unsigned short f2bf(float f) {
    union { float f; unsigned u; } v; v.f = f;
    unsigned u = v.u + 0x7FFFu + ((v.u >> 16) & 1u);
    return (unsigned short)(u >> 16);
}
__device__ __forceinline__ float bl(unsigned u) { return __uint_as_float(u << 16); }
__device__ __forceinline__ float bh(unsigned u) { return __uint_as_float(u & 0xFFFF0000u); }

__device__ __forceinline__ void gload_lds16(const void* g, void* l) {
    __builtin_amdgcn_global_load_lds((const __attribute__((address_space(1))) void*)g,
                                     (__attribute__((address_space(3))) void*)l, 16, 0, 0);
}

// ---------------- x -> bf16 ----------------
__global__ void cvt_x_kernel(const float* __restrict__ x, unsigned short* __restrict__ xb,
                             int n8) {
    int i = blockIdx.x * 256 + threadIdx.x;
    if (i < n8) {
        const float4* p = reinterpret_cast<const float4*>(x) + (size_t)i * 2;
        float4 a = p[0], b = p[1];
        ushort8 o;
        o[0] = f2bf(a.x); o[1] = f2bf(a.y); o[2] = f2bf(a.z); o[3] = f2bf(a.w);
        o[4] = f2bf(b.x); o[5] = f2bf(b.y); o[6] = f2bf(b.z); o[7] = f2bf(b.w);
        *reinterpret_cast<ushort8*>(xb + (size_t)i * 8) = o;
    }
}

// ---------------- weights -> bf16 slices: 0=A1; 1,2=A2; 3,4,5=A3; 6=Cw -------
// slice[s][c][k'] = A[a*128+k'][c]   (Cw: [c][k] as-is)
__global__ void cvt_B_all(const float* __restrict__ A1, const float* __restrict__ A2,
                          const float* __restrict__ A3, const float* __restrict__ Cw,
                          unsigned short* __restrict__ bts) {
    int kg = blockIdx.x;   // 0..895
    int c = threadIdx.x;   // 0..127
    float v;
    int slice, kp;
    if (kg < 128)      { slice = 0; kp = kg; v = A1[(size_t)kg * 128 + c]; }
    else if (kg < 384) { int k = kg - 128; slice = 1 + (k >> 7); kp = k & 127; v = A2[(size_t)k * 128 + c]; }
    else if (kg < 768) { int k = kg - 384; slice = 3 + (k >> 7); kp = k & 127; v = A3[(size_t)k * 128 + c]; }
    else               { int k = kg - 768; slice = 6; kp = k; v = Cw[(size_t)c * 128 + k]; }
    bts[(size_t)slice * 16384 + c * 128 + kp] = f2bf(v);
}

// ---------------- fused counts ----------------
__global__ void count_all_kernel(const int* __restrict__ e1d, const int* __restrict__ e2d,
                                 const int* __restrict__ e3d, int ng1, int ng12, int ngall,
                                 int* __restrict__ counts) {
    int g = blockIdx.x * 256 + threadIdx.x;
    if (g < ng1) atomicAdd(&counts[e1d[g]], 1);
    else if (g < ng12) atomicAdd(&counts[N_NODES + e2d[(size_t)(g - ng1) * 2]], 1);
    else if (g < ngall) atomicAdd(&counts[2 * N_NODES + e3d[(size_t)(g - ng12) * 3]], 1);
}

// ---------------- hierarchical scan ----------------
__global__ __launch_bounds__(256) void scan_p1(const int* __restrict__ counts,
                                               int* __restrict__ partials) {
    __shared__ int red[256];
    int type = blockIdx.y, blk = blockIdx.x, tid = threadIdx.x;
    int base = blk * 4096 + tid * 16;
    int s = 0;
#pragma unroll
    for (int j = 0; j < 16; ++j) {
        int i = base + j;
        s += (i < N_NODES) ? counts[(size_t)type * N_NODES + i] : 0;
    }
    red[tid] = s;
    __syncthreads();
    for (int off = 128; off > 0; off >>= 1) {
        if (tid < off) red[tid] += red[tid + off];
        __syncthreads();
    }
    if (tid == 0) partials[type * 32 + blk] = red[0];
}

__global__ void scan_p2(int* __restrict__ partials) {
    int t = threadIdx.x;
    if (t < 3) {
        int run = 0;
        for (int b = 0; b < 25; ++b) {
            int v = partials[t * 32 + b];
            partials[t * 32 + b] = run;
            run += v;
        }
    }
}

__global__ __launch_bounds__(256) void scan_p3(const int* __restrict__ counts,
                                               const int* __restrict__ partials,
                                               int* __restrict__ cursor) {
    __shared__ int tsum[256];
    int type = blockIdx.y, blk = blockIdx.x, tid = threadIdx.x;
    int base = blk * 4096 + tid * 16;
    int v[16];
    int s = 0;
#pragma unroll
    for (int j = 0; j < 16; ++j) {
        int i = base + j;
        v[j] = (i < N_NODES) ? counts[(size_t)type * N_NODES + i] : 0;
        s += v[j];
    }
    tsum[tid] = s;
    __syncthreads();
    for (int off = 1; off < 256; off <<= 1) {
        int t2 = (tid >= off) ? tsum[tid - off] : 0;
        __syncthreads();
        tsum[tid] += t2;
        __syncthreads();
    }
    int run = tsum[tid] - s + partials[type * 32 + blk];
#pragma unroll
    for (int j = 0; j < 16; ++j) {
        int i = base + j;
        if (i < N_NODES) cursor[(size_t)type * N_NODES + i] = run;
        run += v[j];
    }
}

// ---------------- fused counting-sort scatter ----------------
__global__ void scatter_all_kernel(const int* __restrict__ e1d, const int* __restrict__ e2d,
                                   const int* __restrict__ e3d, int ng1, int ng12, int ngall,
                                   int* __restrict__ cursor, int* __restrict__ s1,
                                   int* __restrict__ s2, int* __restrict__ s3) {
    int g = blockIdx.x * 256 + threadIdx.x;
    if (g < ng1) {
        int d = e1d[g];
        s1[atomicAdd(&cursor[d], 1)] = g;
    } else if (g < ng12) {
        int k = g - ng1;
        int d = e2d[(size_t)k * 2];
        s2[atomicAdd(&cursor[N_NODES + d], 1)] = k;
    } else if (g < ngall) {
        int k = g - ng12;
        int d = e3d[(size_t)k * 3];
        s3[atomicAdd(&cursor[2 * N_NODES + d], 1)] = k;
    }
}

// ---------------- dense: Y slices (bf16) + out init (Cw + bias) ----------------
// LDS: [0,32768) 4 x 8192 S buffers (full K=128 of a 128-row tile);
//      [32768, 32768+128*136*2) Ep bf16 staging for Y writes.
__global__ __launch_bounds__(256, 2) void dense_y_kernel(
    const unsigned short* __restrict__ xb, const unsigned short* __restrict__ bts,
    const float* __restrict__ Cb, float* __restrict__ out,
    unsigned short* __restrict__ ybf, int nnodes)
{
    constexpr int EPOFF = 32768;
    __shared__ __align__(16) char smem[32768 + 128 * 136 * 2];
    unsigned short* Ep = (unsigned short*)(smem + EPOFF);

    const int tid = threadIdx.x;
    const int w = tid >> 6, l = tid & 63;
    const int g0 = blockIdx.x * 128;
    const int lrow = l & 15, lk = l >> 4;
    const int wr = (w & 1) * 64, wc = (w >> 1) * 64;

    const int q = (((l & 7) ^ (l >> 3)) << 4);
    const int inner = q & 63;
    const int rpq = ((l >> 3) << 1) + (q >> 6);

    int aoff[4];
#pragma unroll
    for (int mi = 0; mi < 4; ++mi) {
        int r = wr + mi * 16 + lrow;
        int P = r >> 1;
        aoff[mi] = P * 128 + ((((r & 1) << 6) | (lk << 4)) ^ ((P & 7) << 4));
    }

    // stage whole 128x128 x-tile (4 k-chunks into 4 buffers)
#pragma unroll
    for (int kc = 0; kc < 4; ++kc) {
        const int f0b = kc * 64;
#pragma unroll
        for (int i = 0; i < 2; ++i) {
            int u = w * 2 + i;
            int r = u * 16 + rpq;
            int gg = g0 + r;
            int node = (gg < nnodes) ? gg : 0;
            gload_lds16((const char*)xb + (size_t)node * 256 + f0b + inner,
                        smem + kc * 8192 + u * 1024);
        }
    }
    asm volatile("s_waitcnt vmcnt(0)" ::: "memory");
    __builtin_amdgcn_s_barrier();
    asm volatile("" ::: "memory");

    for (int s = 0; s < 6; ++s) {
        f32x4 acc[4][4];
#pragma unroll
        for (int mi = 0; mi < 4; ++mi)
#pragma unroll
            for (int ni = 0; ni < 4; ++ni) acc[mi][ni] = (f32x4){0.f, 0.f, 0.f, 0.f};
#pragma unroll
        for (int t = 0; t < 4; ++t) {
            bf16x8 af[4], bg[4];
#pragma unroll
            for (int mi = 0; mi < 4; ++mi)
                af[mi] = *reinterpret_cast<const bf16x8*>(smem + t * 8192 + aoff[mi]);
#pragma unroll
            for (int ni = 0; ni < 4; ++ni)
                bg[ni] = *reinterpret_cast<const bf16x8*>(
                    bts + (size_t)s * 16384 + (wc + ni * 16 + lrow) * 128 + t * 32 + lk * 8);
#pragma unroll
            for (int mi = 0; mi < 4; ++mi)
#pragma unroll
                for (int ni = 0; ni < 4; ++ni)
                    acc[mi][ni] = __builtin_amdgcn_mfma_f32_16x16x32_bf16(
                        af[mi], bg[ni], acc[mi][ni], 0, 0, 0);
        }
        // stage acc -> Ep (bf16)
#pragma unroll
        for (int mi = 0; mi < 4; ++mi)
#pragma unroll
            for (int ni = 0; ni < 4; ++ni) {
                const int col = wc + ni * 16 + lrow;
#pragma unroll
                for (int reg = 0; reg < 4; ++reg) {
                    int row = wr + mi * 16 + lk * 4 + reg;
                    Ep[row * 136 + col] = f2bf(acc[mi][ni][reg]);
                }
            }
        __syncthreads();
        // coalesced copy Ep -> ybf[node][s][*]
#pragma unroll
        for (int i = 0; i < 8; ++i) {
            int c = tid + i * 256;     // 0..2047
            int r = c >> 4;            // row
            int off = (c & 15) * 8;    // col
            if (g0 + r < nnodes)
                *reinterpret_cast<ushort8*>(ybf + ((size_t)(g0 + r) * 6 + s) * 128 + off) =
                    *reinterpret_cast<const ushort8*>(Ep + r * 136 + off);
        }
        __syncthreads();
    }

    // Cw slice (s=6): out = x@CwT + Cb, direct f32 stores
    {
        f32x4 acc[4][4];
#pragma unroll
        for (int mi = 0; mi < 4; ++mi)
#pragma unroll
            for (int ni = 0; ni < 4; ++ni) acc[mi][ni] = (f32x4){0.f, 0.f, 0.f, 0.f};
#pragma unroll
        for (int t = 0; t < 4; ++t) {
            bf16x8 af[4], bg[4];
#pragma unroll
            for (int mi = 0; mi < 4; ++mi)
                af[mi] = *reinterpret_cast<const bf16x8*>(smem + t * 8192 + aoff[mi]);
#pragma unroll
            for (int ni = 0; ni < 4; ++ni)
                bg[ni] = *reinterpret_cast<const bf16x8*>(
                    bts + (size_t)6 * 16384 + (wc + ni * 16 + lrow) * 128 + t * 32 + lk * 8);
#pragma unroll
            for (int mi = 0; mi < 4; ++mi)
#pragma unroll
                for (int ni = 0; ni < 4; ++ni)
                    acc[mi][ni] = __builtin_amdgcn_mfma_f32_16x16x32_bf16(
                        af[mi], bg[ni], acc[mi][ni], 0, 0, 0);
        }
        float bv[4];
#pragma unroll
        for (int ni = 0; ni < 4; ++ni) bv[ni] = Cb[wc + ni * 16 + lrow];
#pragma unroll
        for (int mi = 0; mi < 4; ++mi)
#pragma unroll
            for (int reg = 0; reg < 4; ++reg) {
                int g = g0 + wr + mi * 16 + lk * 4 + reg;
                if (g < nnodes) {
#pragma unroll
                    for (int ni = 0; ni < 4; ++ni)
                        out[(size_t)g * DIM + wc + ni * 16 + lrow] = acc[mi][ni][reg] + bv[ni];
                }
            }
    }
}

// ---------------- dest-centric aggregation: zero atomics ----------------
// One wave per dest; two half-waves process alternate groups of the CSR segment;
// lane sl (0..31) owns cols 4sl..4sl+3 (reads 8B of bf16 Y per row).
__global__ __launch_bounds__(256) void aggregate_kernel(
    const unsigned short* __restrict__ ybf,
    const int* __restrict__ e1, const int* __restrict__ e2, const int* __restrict__ e3,
    const int* __restrict__ s1, const int* __restrict__ s2, const int* __restrict__ s3,
    const int* __restrict__ counts, const int* __restrict__ ends,
    float* __restrict__ out)
{
    int d = blockIdx.x * 4 + (threadIdx.x >> 6);
    if (d >= N_NODES) return;
    const int l = threadIdx.x & 63;
    const int hw = l >> 5, sl = l & 31;
    float4 acc = {0.f, 0.f, 0.f, 0.f};

    // type 1 (slice 0)
    {
        int cnt = counts[d];
        if (cnt) {
            int end = ends[d], start = end - cnt;
            float4 p = {0.f, 0.f, 0.f, 0.f};
            for (int i = start + hw; i < end; i += 2) {
                int g = s1[i];
                int src = e1[g];
                uint2 v = *reinterpret_cast<const uint2*>(ybf + (size_t)src * 768 + sl * 4);
                p.x += bl(v.x); p.y += bh(v.x); p.z += bl(v.y); p.w += bh(v.y);
            }
            float inv = 1.f / (float)cnt;
            acc.x += p.x * inv; acc.y += p.y * inv; acc.z += p.z * inv; acc.w += p.w * inv;
        }
    }
    // type 2 (slices 1,2)
    {
        int cnt = counts[N_NODES + d];
        if (cnt) {
            int end = ends[N_NODES + d], start = end - cnt;
            float4 p = {0.f, 0.f, 0.f, 0.f};
            for (int i = start + hw; i < end; i += 2) {
                int g = s2[i];
                int sa = e2[(size_t)g * 2], sb = e2[(size_t)g * 2 + 1];
                uint2 v0 = *reinterpret_cast<const uint2*>(ybf + (size_t)sa * 768 + 128 + sl * 4);
                uint2 v1 = *reinterpret_cast<const uint2*>(ybf + (size_t)sb * 768 + 256 + sl * 4);
                p.x += bl(v0.x) + bl(v1.x); p.y += bh(v0.x) + bh(v1.x);
                p.z += bl(v0.y) + bl(v1.y); p.w += bh(v0.y) + bh(v1.y);
            }
            float inv = 1.f / (float)cnt;
            acc.x += p.x * inv; acc.y += p.y * inv; acc.z += p.z * inv; acc.w += p.w * inv;
        }
    }
    // type 3 (slices 3,4,5)
    {
        int cnt = counts[2 * N_NODES + d];
        if (cnt) {
            int end = ends[2 * N_NODES + d], start = end - cnt;
            float4 p = {0.f, 0.f, 0.f, 0.f};
            for (int i = start + hw; i < end; i += 2) {
                int g = s3[i];
                int sa = e3[(size_t)g * 3], sb = e3[(size_t)g * 3 + 1], sc = e3[(size_t)g * 3 + 2];
                uint2 v0 = *reinterpret_cast<const uint2*>(ybf + (size_t)sa * 768 + 384 + sl * 4);
                uint2 v1 = *reinterpret_cast<const uint2*>(ybf + (size_t)sb * 768 + 512 + sl * 4);
                uint2 v2 = *reinterpret_cast<const uint2*>(ybf + (size_t)sc * 768 + 640 + sl * 4);
                p.x += bl(v0.x) + bl(v1.x) + bl(v2.x);
                p.y += bh(v0.x) + bh(v1.x) + bh(v2.x);
                p.z += bl(v0.y) + bl(v1.y) + bl(v2.y);
                p.w += bh(v0.y) + bh(v1.y) + bh(v2.y);
            }
            float inv = 1.f / (float)cnt;
            acc.x += p.x * inv; acc.y += p.y * inv; acc.z += p.z * inv; acc.w += p.w * inv;
        }
    }
    // merge half-waves
    acc.x += __shfl_xor(acc.x, 32);
    acc.y += __shfl_xor(acc.y, 32);
    acc.z += __shfl_xor(acc.z, 32);
    acc.w += __shfl_xor(acc.w, 32);
    if (l < 32) {
        float4* op = reinterpret_cast<float4*>(out + (size_t)d * DIM + sl * 4);
        float4 o = *op;
        o.x += acc.x; o.y += acc.y; o.z += acc.z; o.w += acc.w;
        *op = o;
    }
}

// ---------------- FALLBACK (round-3 structure) if ws too small ----------------
template <int ARITY, int MODE>
__global__ __launch_bounds__(256, 2) void hgnn_mfma_fb(
    const unsigned short* __restrict__ xb,
    const int* __restrict__ idx0,
    const int* __restrict__ idx1,
    const int* __restrict__ sorted,
    const unsigned short* __restrict__ BTs,  // slice layout [a][128][128]
    const int* __restrict__ counts,
    const float* __restrict__ bias,
    float* __restrict__ out,
    int ngroups)
{
    constexpr int NSTEPS = 4 * ARITY;
    constexpr int SOFF = 0, TOFF = 16384, NOFF = 32768, DOFF = 34304, IOFF = 34816;
    __shared__ __align__(16) char smem[35328];
    int* nodebuf = (int*)(smem + NOFF);
    int* destbuf = (int*)(smem + DOFF);
    float* invbuf = (float*)(smem + IOFF);

    const int tid = threadIdx.x;
    const int w = tid >> 6, l = tid & 63;
    const int g0 = blockIdx.x * 128;
    const int lrow = l & 15, lk = l >> 4;
    const int wr = (w & 1) * 64, wc = (w >> 1) * 64;

    if (MODE == 0) {
        if (tid < 128) {
            int g = g0 + tid;
            int sg = (g < ngroups) ? sorted[g] : 0;
            int d = (g < ngroups) ? idx1[(size_t)sg * ARITY] : -1;
            destbuf[tid] = d;
            invbuf[tid] = (g < ngroups) ? (1.0f / (float)counts[d]) : 0.f;
#pragma unroll
            for (int a = 0; a < ARITY; ++a)
                nodebuf[a * 128 + tid] = (g < ngroups) ? idx0[(size_t)sg * ARITY + a] : 0;
        }
        __syncthreads();
    }

    const int q = (((l & 7) ^ (l >> 3)) << 4);
    const int inner = q & 63;
    const int rpq = ((l >> 3) << 1) + (q >> 6);

    int aoff[4], boff[4];
#pragma unroll
    for (int mi = 0; mi < 4; ++mi) {
        int r = wr + mi * 16 + lrow;
        int P = r >> 1;
        aoff[mi] = P * 128 + ((((r & 1) << 6) | (lk << 4)) ^ ((P & 7) << 4));
        int c = wc + mi * 16 + lrow;
        int Pc = c >> 1;
        boff[mi] = Pc * 128 + ((((c & 1) << 6) | (lk << 4)) ^ ((Pc & 7) << 4));
    }

    f32x4 acc[4][4];
#pragma unroll
    for (int mi = 0; mi < 4; ++mi)
#pragma unroll
        for (int ni = 0; ni < 4; ++ni) acc[mi][ni] = (f32x4){0.f, 0.f, 0.f, 0.f};

    auto STAGE = [&](int kc, int buf) {
        const int a = kc >> 2;
        const int f0b = (kc & 3) * 64;
#pragma unroll
        for (int i = 0; i < 2; ++i) {
            int u = w * 2 + i;
            int r = u * 16 + rpq;
            int node;
            if (MODE == 1) {
                int gg = g0 + r;
                node = (gg < ngroups) ? gg : 0;
            } else {
                node = nodebuf[a * 128 + r];
            }
            gload_lds16((const char*)xb + (size_t)node * 256 + f0b + inner,
                        smem + SOFF + buf * 8192 + u * 1024);
            gload_lds16((const char*)BTs + (size_t)a * 32768 + (size_t)r * 256 + f0b + inner,
                        smem + TOFF + buf * 8192 + u * 1024);
        }
    };

    STAGE(0, 0);
    __syncthreads();
    for (int t = 0; t < NSTEPS; ++t) {
        const int buf = t & 1;
        if (t + 1 < NSTEPS) STAGE(t + 1, buf ^ 1);
        bf16x8 af[4], bg[4];
#pragma unroll
        for (int mi = 0; mi < 4; ++mi)
            af[mi] = *reinterpret_cast<const bf16x8*>(smem + SOFF + buf * 8192 + aoff[mi]);
#pragma unroll
        for (int ni = 0; ni < 4; ++ni)
            bg[ni] = *reinterpret_cast<const bf16x8*>(smem + TOFF + buf * 8192 + boff[ni]);
#pragma unroll
        for (int mi = 0; mi < 4; ++mi)
#pragma unroll
            for (int ni = 0; ni < 4; ++ni)
                acc[mi][ni] = __builtin_amdgcn_mfma_f32_16x16x32_bf16(
                    af[mi], bg[ni], acc[mi][ni], 0, 0, 0);
        __syncthreads();
    }

    if (MODE == 1) {
        float bv[4];
#pragma unroll
        for (int ni = 0; ni < 4; ++ni) bv[ni] = bias[wc + ni * 16 + lrow];
#pragma unroll
        for (int mi = 0; mi < 4; ++mi)
#pragma unroll
            for (int reg = 0; reg < 4; ++reg) {
                int g = g0 + wr + mi * 16 + lk * 4 + reg;
                if (g < ngroups) {
#pragma unroll
                    for (int ni = 0; ni < 4; ++ni)
                        out[(size_t)g * DIM + wc + ni * 16 + lrow] = acc[mi][ni][reg] + bv[ni];
                }
            }
    } else {
        float* Ep = (float*)smem;  // [32][132]
#pragma unroll
        for (int c0 = 0; c0 < 128; c0 += 32) {
            if ((w & 1) == (c0 >> 6)) {
                const int m0 = (c0 & 63) >> 4;
#pragma unroll
                for (int mm = 0; mm < 2; ++mm) {
                    const int mi = m0 + mm;
                    const int lr = mm * 16 + lk * 4;
#pragma unroll
                    for (int ni = 0; ni < 4; ++ni) {
                        const int col = wc + ni * 16 + lrow;
#pragma unroll
                        for (int reg = 0; reg < 4; ++reg)
                            Ep[(lr + reg) * 132 + col] = acc[mi][ni][reg];
                    }
                }
            }
            __syncthreads();
            int cur = -1;
            float r0 = 0.f, r1 = 0.f;
#pragma unroll
            for (int r = 0; r < 8; ++r) {
                int row = w * 8 + r;
                int g = g0 + c0 + row;
                if (g < ngroups) {
                    int d = destbuf[c0 + row];
                    float inv = invbuf[c0 + row];
                    if (d != cur) {
                        if (cur >= 0) {
                            float* op = out + (size_t)cur * DIM;
                            __hip_atomic_fetch_add(&op[l], r0, __ATOMIC_RELAXED,
                                                   __HIP_MEMORY_SCOPE_AGENT);
                            __hip_atomic_fetch_add(&op[l + 64], r1, __ATOMIC_RELAXED,
                                                   __HIP_MEMORY_SCOPE_AGENT);
                        }
                        cur = d;
                        r0 = 0.f;
                        r1 = 0.f;
                    }
                    r0 += Ep[row * 132 + l] * inv;
                    r1 += Ep[row * 132 + 64 + l] * inv;
                }
            }
            if (cur >= 0) {
                float* op = out + (size_t)cur * DIM;
                __hip_atomic_fetch_add(&op[l], r0, __ATOMIC_RELAXED,
                                       __HIP_MEMORY_SCOPE_AGENT);
                __hip_atomic_fetch_add(&op[l + 64], r1, __ATOMIC_RELAXED,
                                       __HIP_MEMORY_SCOPE_AGENT);
            }
            __syncthreads();
        }
    }
}

extern "C" void kernel_launch(void* const* d_in, const int* in_sizes, int n_in,
                              void* d_out, int out_size, void* d_ws, size_t ws_size,
                              hipStream_t stream) {
    const float* x  = (const float*)d_in[0];
    const int*   e1 = (const int*)d_in[1];
    const int*   e2 = (const int*)d_in[2];
    const int*   e3 = (const int*)d_in[3];
    const float* A1 = (const float*)d_in[4];
    const float* A2 = (const float*)d_in[5];
    const float* A3 = (const float*)d_in[6];
    const float* Cw = (const float*)d_in[7];
    const float* Cb = (const float*)d_in[8];
    float* out = (float*)d_out;

    const int ne1 = in_sizes[1] / 2, ne2 = in_sizes[2] / 2, ne3 = in_sizes[3] / 2;
    const int ng1 = ne1, ng2 = ne2 / 2, ng3 = ne3 / 3;
    const int N = N_NODES;

    int* counts  = (int*)d_ws;          // 3*N
    int* cursor  = counts + 3 * N;      // 3*N
    int* sorted1 = cursor + 3 * N;
    int* sorted2 = sorted1 + ng1;
    int* sorted3 = sorted2 + ng2;
    int* partials = sorted3 + ng3;      // 96 used, pad 128
    unsigned short* bts = (unsigned short*)(partials + 128);  // 7 * 16384
    unsigned short* xb  = bts + 7 * 16384;                    // N*128
    unsigned short* ybf = xb + (size_t)N * 128;               // N*768
    size_t need = (size_t)((char*)(ybf + (size_t)N * 768) - (char*)d_ws);
    const bool full_path = (ws_size >= need);

    hipMemsetAsync(counts, 0, (size_t)3 * N * sizeof(int), stream);
    cvt_x_kernel<<<(N * DIM / 8 + 255) / 256, 256, 0, stream>>>(x, xb, N * DIM / 8);
    cvt_B_all<<<896, 128, 0, stream>>>(A1, A2, A3, Cw, bts);

    const int ngall = ng1 + ng2 + ng3;
    count_all_kernel<<<(ngall + 255) / 256, 256, 0, stream>>>(
        e1 + ne1, e2 + ne2, e3 + ne3, ng1, ng1 + ng2, ngall, counts);
    scan_p1<<<dim3(25, 3), 256, 0, stream>>>(counts, partials);
    scan_p2<<<1, 64, 0, stream>>>(partials);
    scan_p3<<<dim3(25, 3), 256, 0, stream>>>(counts, partials, cursor);
    scatter_all_kernel<<<(ngall + 255) / 256, 256, 0, stream>>>(
        e1 + ne1, e2 + ne2, e3 + ne3, ng1, ng1 + ng2, ngall, cursor,
        sorted1, sorted2, sorted3);

    if (full_path) {
        dense_y_kernel<<<(N + 127) / 128, 256, 0, stream>>>(xb, bts, Cb, out, ybf, N);
        aggregate_kernel<<<(N + 3) / 4, 256, 0, stream>>>(
            ybf, e1, e2, e3, sorted1, sorted2, sorted3, counts, cursor, out);
    } else {
        hgnn_mfma_fb<1, 1><<<(N + 127) / 128, 256, 0, stream>>>(
            xb, nullptr, nullptr, nullptr, bts + 6 * 16384, nullptr, Cb, out, N);
        hgnn_mfma_fb<1, 0><<<(ng1 + 127) / 128, 256, 0, stream>>>(
            xb, e1, e1 + ne1, sorted1, bts, counts, nullptr, out, ng1);
        hgnn_mfma_fb<2, 0><<<(ng2 + 127) / 128, 256, 0, stream>>>(
            xb, e2, e2 + ne2, sorted2, bts + 16384, counts + N, nullptr, out, ng2);
        hgnn_mfma_fb<3, 0><<<(ng3 + 127) / 128, 256, 0, stream>>>(
            xb, e3, e3 + ne3, sorted3, bts + 3 * 16384, counts + 2 * N, nullptr, out, ng3);
    }
}

// Round 6
// 263.701 us; speedup vs baseline: 1.3975x; 1.1776x over previous
//
#include <hip/hip_runtime.h>

#define N_NODES 100000
#define DIM 128

typedef __attribute__((ext_vector_type(8))) short bf16x8;
typedef __attribute__((ext_vector_type(4))) float f32x4;
typedef __attribute__((ext_vector_type(8))) unsigned short ushort8;

__device__ __forceinline__ unsigned short f2bf(float f) {
    union { float f; unsigned u; } v; v.f = f;
    unsigned u = v.u + 0x7FFFu + ((v.u >> 16) & 1u);
    return (unsigned short)(u >> 16);
}
__device__ __forceinline__ float bl(unsigned u) { return __uint_as_float(u << 16); }
__device__ __forceinline__ float bh(unsigned u) { return __uint_as_float(u & 0xFFFF0000u); }

__device__ __forceinline__ void gload_lds16(const void* g, void* l) {
    __builtin_amdgcn_global_load_lds((const __attribute__((address_space(1))) void*)g,
                                     (__attribute__((address_space(3))) void*)l, 16, 0, 0);
}

__device__ __forceinline__ void acc2(float4& a, uint2 v) {
    a.x += bl(v.x); a.y += bh(v.x); a.z += bl(v.y); a.w += bh(v.y);
}
__device__ __forceinline__ void red4(float4& a) {
    a.x += __shfl_xor(a.x, 32); a.y += __shfl_xor(a.y, 32);
    a.z += __shfl_xor(a.z, 32); a.w += __shfl_xor(a.w, 32);
}
__device__ __forceinline__ uint2 pack4(float4 a) {
    uint2 r;
    r.x = (unsigned)f2bf(a.x) | ((unsigned)f2bf(a.y) << 16);
    r.y = (unsigned)f2bf(a.z) | ((unsigned)f2bf(a.w) << 16);
    return r;
}

// ---------------- fused x->bf16 + degree counts ----------------
__global__ void cvt_count_kernel(const float* __restrict__ x, unsigned short* __restrict__ xb,
                                 int n8, const int* __restrict__ e1d,
                                 const int* __restrict__ e2d, const int* __restrict__ e3d,
                                 int ng1, int ng12, int ngall, int* __restrict__ counts) {
    int i = blockIdx.x * 256 + threadIdx.x;
    if (i < n8) {
        const float4* p = reinterpret_cast<const float4*>(x) + (size_t)i * 2;
        float4 a = p[0], b = p[1];
        ushort8 o;
        o[0] = f2bf(a.x); o[1] = f2bf(a.y); o[2] = f2bf(a.z); o[3] = f2bf(a.w);
        o[4] = f2bf(b.x); o[5] = f2bf(b.y); o[6] = f2bf(b.z); o[7] = f2bf(b.w);
        *reinterpret_cast<ushort8*>(xb + (size_t)i * 8) = o;
    }
    if (i < ng1) atomicAdd(&counts[e1d[i]], 1);
    else if (i < ng12) atomicAdd(&counts[N_NODES + e2d[(size_t)(i - ng1) * 2]], 1);
    else if (i < ngall) atomicAdd(&counts[2 * N_NODES + e3d[(size_t)(i - ng12) * 3]], 1);
}

// ---------------- weights -> bf16 slices: 0=A1; 1,2=A2; 3,4,5=A3; 6=Cw -------
__global__ void cvt_B_all(const float* __restrict__ A1, const float* __restrict__ A2,
                          const float* __restrict__ A3, const float* __restrict__ Cw,
                          unsigned short* __restrict__ bts) {
    int kg = blockIdx.x;   // 0..895
    int c = threadIdx.x;   // 0..127
    float v;
    int slice, kp;
    if (kg < 128)      { slice = 0; kp = kg; v = A1[(size_t)kg * 128 + c]; }
    else if (kg < 384) { int k = kg - 128; slice = 1 + (k >> 7); kp = k & 127; v = A2[(size_t)k * 128 + c]; }
    else if (kg < 768) { int k = kg - 384; slice = 3 + (k >> 7); kp = k & 127; v = A3[(size_t)k * 128 + c]; }
    else               { int k = kg - 768; slice = 6; kp = k; v = Cw[(size_t)c * 128 + k]; }
    bts[(size_t)slice * 16384 + c * 128 + kp] = f2bf(v);
}

// ---------------- hierarchical scan ----------------
__global__ __launch_bounds__(256) void scan_p1(const int* __restrict__ counts,
                                               int* __restrict__ partials) {
    __shared__ int red[256];
    int type = blockIdx.y, blk = blockIdx.x, tid = threadIdx.x;
    int base = blk * 4096 + tid * 16;
    int s = 0;
#pragma unroll
    for (int j = 0; j < 16; ++j) {
        int i = base + j;
        s += (i < N_NODES) ? counts[(size_t)type * N_NODES + i] : 0;
    }
    red[tid] = s;
    __syncthreads();
    for (int off = 128; off > 0; off >>= 1) {
        if (tid < off) red[tid] += red[tid + off];
        __syncthreads();
    }
    if (tid == 0) partials[type * 32 + blk] = red[0];
}

// pass 3 with the 25-element cross-block scan inlined (drops scan_p2 launch)
__global__ __launch_bounds__(256) void scan_p3(const int* __restrict__ counts,
                                               const int* __restrict__ partials,
                                               int* __restrict__ cursor) {
    __shared__ int tsum[256];
    __shared__ int baseoff;
    int type = blockIdx.y, blk = blockIdx.x, tid = threadIdx.x;
    if (tid == 0) {
        int r = 0;
        for (int b = 0; b < blk; ++b) r += partials[type * 32 + b];
        baseoff = r;
    }
    int base = blk * 4096 + tid * 16;
    int v[16];
    int s = 0;
#pragma unroll
    for (int j = 0; j < 16; ++j) {
        int i = base + j;
        v[j] = (i < N_NODES) ? counts[(size_t)type * N_NODES + i] : 0;
        s += v[j];
    }
    tsum[tid] = s;
    __syncthreads();
    for (int off = 1; off < 256; off <<= 1) {
        int t2 = (tid >= off) ? tsum[tid - off] : 0;
        __syncthreads();
        tsum[tid] += t2;
        __syncthreads();
    }
    int run = tsum[tid] - s + baseoff;
#pragma unroll
    for (int j = 0; j < 16; ++j) {
        int i = base + j;
        if (i < N_NODES) cursor[(size_t)type * N_NODES + i] = run;
        run += v[j];
    }
}

// ---------------- counting-sort scatter, storing packed SRC ids ----------------
__global__ void scatter_all_kernel(const int* __restrict__ e1, const int* __restrict__ e2,
                                   const int* __restrict__ e3, int ne1, int ne2, int ne3,
                                   int ng1, int ng12, int ngall, int* __restrict__ cursor,
                                   int* __restrict__ s1, int2* __restrict__ s2,
                                   int4* __restrict__ s3) {
    int g = blockIdx.x * 256 + threadIdx.x;
    if (g < ng1) {
        int d = e1[ne1 + g];
        s1[atomicAdd(&cursor[d], 1)] = e1[g];
    } else if (g < ng12) {
        int k = g - ng1;
        int d = e2[ne2 + 2 * (size_t)k];
        int2 v; v.x = e2[2 * (size_t)k]; v.y = e2[2 * (size_t)k + 1];
        s2[atomicAdd(&cursor[N_NODES + d], 1)] = v;
    } else if (g < ngall) {
        int k = g - ng12;
        int d = e3[ne3 + 3 * (size_t)k];
        int4 v; v.x = e3[3 * (size_t)k]; v.y = e3[3 * (size_t)k + 1];
        v.z = e3[3 * (size_t)k + 2]; v.w = 0;
        s3[atomicAdd(&cursor[2 * N_NODES + d], 1)] = v;
    }
}

// ---------------- dest-centric x-space aggregation ----------------
// One wave per dest; half-waves walk alternate groups; lane sl owns cols 4sl..4sl+3.
// Output: gbf[slice][dest][128] bf16, per-type 1/cnt folded in.
__global__ __launch_bounds__(256) void aggregate_x_kernel(
    const unsigned short* __restrict__ xb,
    const int* __restrict__ s1, const int2* __restrict__ s2, const int4* __restrict__ s3,
    const int* __restrict__ counts, const int* __restrict__ ends,
    unsigned short* __restrict__ gbf)
{
    int d = blockIdx.x * 4 + (threadIdx.x >> 6);
    if (d >= N_NODES) return;
    const int l = threadIdx.x & 63, hw = l >> 5, sl = l & 31;
    float4 a0 = {0,0,0,0}, a1 = {0,0,0,0}, a2 = {0,0,0,0};
    float4 a3 = {0,0,0,0}, a4 = {0,0,0,0}, a5 = {0,0,0,0};

    int c1 = counts[d], c2 = counts[N_NODES + d], c3 = counts[2 * N_NODES + d];
    int e1e = ends[d], e2e = ends[N_NODES + d], e3e = ends[2 * N_NODES + d];

    if (c1) {
        for (int i = e1e - c1 + hw; i < e1e; i += 2) {
            uint2 v = *reinterpret_cast<const uint2*>(xb + (size_t)s1[i] * 128 + sl * 4);
            acc2(a0, v);
        }
        float inv = 1.f / (float)c1;
        a0.x *= inv; a0.y *= inv; a0.z *= inv; a0.w *= inv;
    }
    if (c2) {
        for (int i = e2e - c2 + hw; i < e2e; i += 2) {
            int2 p = s2[i];
            uint2 va = *reinterpret_cast<const uint2*>(xb + (size_t)p.x * 128 + sl * 4);
            uint2 vb = *reinterpret_cast<const uint2*>(xb + (size_t)p.y * 128 + sl * 4);
            acc2(a1, va); acc2(a2, vb);
        }
        float inv = 1.f / (float)c2;
        a1.x *= inv; a1.y *= inv; a1.z *= inv; a1.w *= inv;
        a2.x *= inv; a2.y *= inv; a2.z *= inv; a2.w *= inv;
    }
    if (c3) {
        for (int i = e3e - c3 + hw; i < e3e; i += 2) {
            int4 p = s3[i];
            uint2 va = *reinterpret_cast<const uint2*>(xb + (size_t)p.x * 128 + sl * 4);
            uint2 vb = *reinterpret_cast<const uint2*>(xb + (size_t)p.y * 128 + sl * 4);
            uint2 vc = *reinterpret_cast<const uint2*>(xb + (size_t)p.z * 128 + sl * 4);
            acc2(a3, va); acc2(a4, vb); acc2(a5, vc);
        }
        float inv = 1.f / (float)c3;
        a3.x *= inv; a3.y *= inv; a3.z *= inv; a3.w *= inv;
        a4.x *= inv; a4.y *= inv; a4.z *= inv; a4.w *= inv;
        a5.x *= inv; a5.y *= inv; a5.z *= inv; a5.w *= inv;
    }
    red4(a0); red4(a1); red4(a2); red4(a3); red4(a4); red4(a5);
    if (hw == 0) {
        *reinterpret_cast<uint2*>(gbf + ((size_t)0 * N_NODES + d) * 128 + sl * 4) = pack4(a0);
        *reinterpret_cast<uint2*>(gbf + ((size_t)1 * N_NODES + d) * 128 + sl * 4) = pack4(a1);
        *reinterpret_cast<uint2*>(gbf + ((size_t)2 * N_NODES + d) * 128 + sl * 4) = pack4(a2);
        *reinterpret_cast<uint2*>(gbf + ((size_t)3 * N_NODES + d) * 128 + sl * 4) = pack4(a3);
        *reinterpret_cast<uint2*>(gbf + ((size_t)4 * N_NODES + d) * 128 + sl * 4) = pack4(a4);
        *reinterpret_cast<uint2*>(gbf + ((size_t)5 * N_NODES + d) * 128 + sl * 4) = pack4(a5);
    }
}

// ---------------- dense output GEMM: out = G'@concat(A) + x@CwT + Cb ----------
// K = 7 chunks of 128 (6 G' slices + x/Cw). LDS: 2 x 32KB double buffer,
// each 32KB chunk = 4 sub-buffers of 8KB (128 rows x 64B), XOR-swizzled.
__global__ __launch_bounds__(256, 2) void gemm_out_kernel(
    const unsigned short* __restrict__ xb, const unsigned short* __restrict__ gbf,
    const unsigned short* __restrict__ bts, const float* __restrict__ Cb,
    float* __restrict__ out, int nnodes)
{
    __shared__ __align__(16) char smem[65536];

    const int tid = threadIdx.x;
    const int w = tid >> 6, l = tid & 63;
    const int g0 = blockIdx.x * 128;
    const int lrow = l & 15, lk = l >> 4;
    const int wr = (w & 1) * 64, wc = (w >> 1) * 64;

    const int q = (((l & 7) ^ (l >> 3)) << 4);
    const int inner = q & 63;
    const int rpq = ((l >> 3) << 1) + (q >> 6);

    int aoff[4];
#pragma unroll
    for (int mi = 0; mi < 4; ++mi) {
        int r = wr + mi * 16 + lrow;
        int P = r >> 1;
        aoff[mi] = P * 128 + ((((r & 1) << 6) | (lk << 4)) ^ ((P & 7) << 4));
    }

    f32x4 acc[4][4];
#pragma unroll
    for (int mi = 0; mi < 4; ++mi)
#pragma unroll
        for (int ni = 0; ni < 4; ++ni) acc[mi][ni] = (f32x4){0.f, 0.f, 0.f, 0.f};

    auto STAGE = [&](int c, int buf) {
#pragma unroll
        for (int i = 0; i < 2; ++i) {
            int u = w * 2 + i;
            int r = u * 16 + rpq;
            int row = (g0 + r < nnodes) ? g0 + r : 0;
            const char* src = (c < 6)
                ? (const char*)gbf + ((size_t)c * N_NODES + row) * 256
                : (const char*)xb + (size_t)row * 256;
#pragma unroll
            for (int t2 = 0; t2 < 4; ++t2)
                gload_lds16(src + t2 * 64 + inner, smem + buf * 32768 + t2 * 8192 + u * 1024);
        }
    };

    STAGE(0, 0);
    asm volatile("s_waitcnt vmcnt(0)" ::: "memory");
    __builtin_amdgcn_s_barrier();
    asm volatile("" ::: "memory");

    for (int c = 0; c < 7; ++c) {
        if (c + 1 < 7) STAGE(c + 1, (c + 1) & 1);
        const int bb = (c & 1) * 32768;
#pragma unroll
        for (int ks = 0; ks < 4; ++ks) {
            bf16x8 af[4], bg[4];
#pragma unroll
            for (int mi = 0; mi < 4; ++mi)
                af[mi] = *reinterpret_cast<const bf16x8*>(smem + bb + ks * 8192 + aoff[mi]);
#pragma unroll
            for (int ni = 0; ni < 4; ++ni)
                bg[ni] = *reinterpret_cast<const bf16x8*>(
                    bts + (size_t)c * 16384 + (wc + ni * 16 + lrow) * 128 + ks * 32 + lk * 8);
            __builtin_amdgcn_s_setprio(1);
#pragma unroll
            for (int mi = 0; mi < 4; ++mi)
#pragma unroll
                for (int ni = 0; ni < 4; ++ni)
                    acc[mi][ni] = __builtin_amdgcn_mfma_f32_16x16x32_bf16(
                        af[mi], bg[ni], acc[mi][ni], 0, 0, 0);
            __builtin_amdgcn_s_setprio(0);
        }
        asm volatile("s_waitcnt vmcnt(0)" ::: "memory");
        __builtin_amdgcn_s_barrier();
        asm volatile("" ::: "memory");
    }

    float bv[4];
#pragma unroll
    for (int ni = 0; ni < 4; ++ni) bv[ni] = Cb[wc + ni * 16 + lrow];
#pragma unroll
    for (int mi = 0; mi < 4; ++mi)
#pragma unroll
        for (int reg = 0; reg < 4; ++reg) {
            int g = g0 + wr + mi * 16 + lk * 4 + reg;
            if (g < nnodes) {
#pragma unroll
                for (int ni = 0; ni < 4; ++ni)
                    out[(size_t)g * DIM + wc + ni * 16 + lrow] = acc[mi][ni][reg] + bv[ni];
            }
        }
}

extern "C" void kernel_launch(void* const* d_in, const int* in_sizes, int n_in,
                              void* d_out, int out_size, void* d_ws, size_t ws_size,
                              hipStream_t stream) {
    const float* x  = (const float*)d_in[0];
    const int*   e1 = (const int*)d_in[1];
    const int*   e2 = (const int*)d_in[2];
    const int*   e3 = (const int*)d_in[3];
    const float* A1 = (const float*)d_in[4];
    const float* A2 = (const float*)d_in[5];
    const float* A3 = (const float*)d_in[6];
    const float* Cw = (const float*)d_in[7];
    const float* Cb = (const float*)d_in[8];
    float* out = (float*)d_out;

    const int ne1 = in_sizes[1] / 2, ne2 = in_sizes[2] / 2, ne3 = in_sizes[3] / 2;
    const int ng1 = ne1, ng2 = ne2 / 2, ng3 = ne3 / 3;
    const int N = N_NODES;

    int*  counts  = (int*)d_ws;                     // 3N
    int*  cursor  = counts + 3 * N;                 // 3N
    int4* s3      = (int4*)(cursor + 3 * N);        // ng3 (16B aligned)
    int2* s2      = (int2*)(s3 + ng3);              // ng2
    int*  s1      = (int*)(s2 + ng2);               // ng1
    int*  partials = s1 + ng1;                      // 96 used, pad 128
    unsigned short* bts = (unsigned short*)(partials + 128);   // 7*16384
    unsigned short* xb  = bts + 7 * 16384;                     // N*128
    unsigned short* gbf = xb + (size_t)N * 128;                // 6*N*128

    const int ngall = ng1 + ng2 + ng3;
    const int n8 = N * DIM / 8;

    hipMemsetAsync(counts, 0, (size_t)3 * N * sizeof(int), stream);
    cvt_count_kernel<<<(n8 + 255) / 256, 256, 0, stream>>>(
        x, xb, n8, e1 + ne1, e2 + ne2, e3 + ne3, ng1, ng1 + ng2, ngall, counts);
    cvt_B_all<<<896, 128, 0, stream>>>(A1, A2, A3, Cw, bts);
    scan_p1<<<dim3(25, 3), 256, 0, stream>>>(counts, partials);
    scan_p3<<<dim3(25, 3), 256, 0, stream>>>(counts, partials, cursor);
    scatter_all_kernel<<<(ngall + 255) / 256, 256, 0, stream>>>(
        e1, e2, e3, ne1, ne2, ne3, ng1, ng1 + ng2, ngall, cursor, s1, s2, s3);
    aggregate_x_kernel<<<(N + 3) / 4, 256, 0, stream>>>(
        xb, s1, s2, s3, counts, cursor, gbf);
    gemm_out_kernel<<<(N + 127) / 128, 256, 0, stream>>>(xb, gbf, bts, Cb, out, N);
}